// Round 7
// baseline (263.973 us; speedup 1.0000x reference)
//
#include <hip/hip_runtime.h>
#include <cstddef>

// Problem constants (match reference)
#define B_   256
#define T_   2048
#define DIM_ 64
#define NC_  16              // chunks per row
#define CS_  (T_ / NC_)      // 128 steps per chunk
#define SG_  16              // step-subgroups per block (256 threads)
#define SPS_ (CS_ / SG_)     // 8 steps per subgroup
// THETA=0.1, MU=0, SIGMA=1 ; sigma/sqrt(2*theta) = sqrt(5)
#define OU_SCALE 2.2360679774997896f

// delta coefficients for step t of row b:
//  x: brownian-increment std (0 if invalid), y: OU-increment std * sqrt(5)
__device__ __forceinline__ float2 delta_pair(const float* __restrict__ tsb, int t) {
    float tk = tsb[t];
    float tp = (t == 0) ? 0.0f : tsb[t - 1];
    float dt = tk - tp;
    float db  = sqrtf(dt);
    // exp(2θ tk) - exp(2θ tp) = exp(2θ tp) * expm1(2θ dt)
    float dou = sqrtf(expf(0.2f * tp) * expm1f(0.2f * dt));
    float cb = (db  <= 0.0f) ? 0.0f : db;
    float co = (dou <= 0.0f) ? 0.0f : dou * OU_SCALE;
    return make_float2(cb, co);
}

// ---------------------------------------------------------------------------
// Kernel 1: per-chunk weighted partials -> workspace ws[b][c][64].
// Grid = B*NC blocks x 256 threads (full occupancy; avoids the ~2.6 TB/s
// 1-block/CU shape measured in r0/r5). The workspace poison-fill is
// UNCONDITIONAL (present in r2/r5 profiles with d_ws untouched), so using
// d_ws is free — this removes the head-row stash, the prefix kernel, and
// all cross-block ordering concerns.
__global__ __launch_bounds__(256) void partial_kernel(
        const float* __restrict__ ts,
        const float* __restrict__ noise,
        float* __restrict__ ws)
{
    __shared__ float2 dlt[CS_];        // 1 KB
    __shared__ float4 red[SG_][16];    // 4 KB

    const int v   = blockIdx.x;
    const int b   = v >> 4;            // v / NC_
    const int c   = v & (NC_ - 1);
    const int tid = threadIdx.x;
    const int sg  = tid >> 4;          // step subgroup (8 contiguous steps)
    const int qi  = tid & 15;          // dim quad index
    const int q   = qi << 2;
    const int t0  = c * CS_;

    const size_t rowbase = (size_t)b * T_ * DIM_;
    const float* np = noise + rowbase + (size_t)(t0 + sg * SPS_) * DIM_ + q;
    float4 r[SPS_];
#pragma unroll
    for (int i = 0; i < SPS_; ++i)
        r[i] = *(const float4*)(np + (size_t)i * DIM_);

    const float* tsb = ts + (size_t)b * T_;
    if (tid < CS_) dlt[tid] = delta_pair(tsb, t0 + tid);
    __syncthreads();

    const bool ou = q >= (DIM_ / 2);
    float4 a = make_float4(0.f, 0.f, 0.f, 0.f);
#pragma unroll
    for (int i = 0; i < SPS_; ++i) {
        float2 d2 = dlt[sg * SPS_ + i];
        float d = ou ? d2.y : d2.x;
        a.x = fmaf(d, r[i].x, a.x);
        a.y = fmaf(d, r[i].y, a.y);
        a.z = fmaf(d, r[i].z, a.z);
        a.w = fmaf(d, r[i].w, a.w);
    }
    red[sg][qi] = a;
    __syncthreads();

    if (tid < 16) {                    // one thread per dim quad
        float4 s = red[0][tid];
#pragma unroll
        for (int k = 1; k < SG_; ++k) {
            float4 t4 = red[k][tid];
            s.x += t4.x; s.y += t4.y; s.z += t4.z; s.w += t4.w;
        }
        *(float4*)(ws + ((size_t)b * NC_ + c) * DIM_ + (tid << 2)) = s;
    }
}

// ---------------------------------------------------------------------------
// Kernel 2: block (b,c) gathers its exclusive base from ws (L2-hot, <=15
// float4 loads per quad-thread), re-reads its noise chunk (L3-hot from K1),
// scans, normalizes, float4 stores. ws is disjoint from out -> no ordering
// hazards beyond the K1->K2 kernel boundary.
__global__ __launch_bounds__(256) void scan_kernel(
        const float* __restrict__ ts,
        const float* __restrict__ noise,
        const float* __restrict__ ws,
        float* __restrict__ out)
{
    __shared__ float4 cof[CS_];        // {d_bm, d_ou*sqrt5, f_bm, f_ou} 2 KB
    __shared__ float4 red[SG_][16];    // 4 KB
    __shared__ float4 basev[16];       // 256 B

    const int v   = blockIdx.x;
    const int b   = v >> 4;
    const int c   = v & (NC_ - 1);
    const int tid = threadIdx.x;
    const int sg  = tid >> 4;
    const int qi  = tid & 15;
    const int q   = qi << 2;
    const int t0  = c * CS_;

    const size_t rowbase = (size_t)b * T_ * DIM_;
    const float* np = noise + rowbase + (size_t)(t0 + sg * SPS_) * DIM_ + q;
    float4 r[SPS_];
#pragma unroll
    for (int i = 0; i < SPS_; ++i)
        r[i] = *(const float4*)(np + (size_t)i * DIM_);

    // cross-chunk exclusive base from workspace partials (written by K1)
    if (sg == 0) {
        float4 s = make_float4(0.f, 0.f, 0.f, 0.f);
        const float* pb = ws + (size_t)b * NC_ * DIM_ + q;
        for (int k = 0; k < c; ++k) {
            float4 p = *(const float4*)(pb + (size_t)k * DIM_);
            s.x += p.x; s.y += p.y; s.z += p.z; s.w += p.w;
        }
        basev[qi] = s;
    }

    const float* tsb = ts + (size_t)b * T_;
    if (tid < CS_) {
        int t = t0 + tid;
        float2 d  = delta_pair(tsb, t);
        float tk  = tsb[t];
        float fb  = 1.0f / (sqrtf(tk) + 1e-8f);
        float em  = expf(-0.1f * tk);                      // exp(-θ t)
        float fo  = em / (sqrtf(-expm1f(-0.2f * tk) * 5.0f) + 1e-8f);
        cof[tid] = make_float4(d.x, d.y, fb, fo);
    }
    __syncthreads();

    // weight in place, accumulate subgroup partial
    const bool ou = q >= (DIM_ / 2);
    float4 s = make_float4(0.f, 0.f, 0.f, 0.f);
#pragma unroll
    for (int i = 0; i < SPS_; ++i) {
        float4 cc = cof[sg * SPS_ + i];
        float d = ou ? cc.y : cc.x;
        r[i].x *= d; r[i].y *= d; r[i].z *= d; r[i].w *= d;
        s.x += r[i].x; s.y += r[i].y; s.z += r[i].z; s.w += r[i].w;
    }
    red[sg][qi] = s;
    __syncthreads();

    // exclusive prefix over earlier subgroups of this chunk + cross-chunk base
    float4 acc = basev[qi];
    for (int k = 0; k < sg; ++k) {
        float4 p = red[k][qi];
        acc.x += p.x; acc.y += p.y; acc.z += p.z; acc.w += p.w;
    }

    // replay from registers, normalize, float4 store
    float* op = out + rowbase + (size_t)(t0 + sg * SPS_) * DIM_ + q;
#pragma unroll
    for (int i = 0; i < SPS_; ++i) {
        float4 cc = cof[sg * SPS_ + i];
        float f = ou ? cc.w : cc.z;
        acc.x += r[i].x; acc.y += r[i].y; acc.z += r[i].z; acc.w += r[i].w;
        *(float4*)(op + (size_t)i * DIM_) =
            make_float4(acc.x * f, acc.y * f, acc.z * f, acc.w * f);
    }
}

// ---------------------------------------------------------------------------
extern "C" void kernel_launch(void* const* d_in, const int* in_sizes, int n_in,
                              void* d_out, int out_size, void* d_ws, size_t ws_size,
                              hipStream_t stream) {
    const float* ts    = (const float*)d_in[0];   // [B,T,1] fp32
    const float* noise = (const float*)d_in[1];   // [B,T,DIM] fp32
    float* out = (float*)d_out;                   // [B,T,DIM] fp32
    float* ws  = (float*)d_ws;                    // 1 MB partials [B][NC][DIM]
    (void)ws_size; (void)in_sizes; (void)n_in; (void)out_size;

    partial_kernel<<<B_ * NC_, 256, 0, stream>>>(ts, noise, ws);
    scan_kernel   <<<B_ * NC_, 256, 0, stream>>>(ts, noise, ws, out);
}

// Round 8
// 258.519 us; speedup vs baseline: 1.0211x; 1.0211x over previous
//
#include <hip/hip_runtime.h>
#include <cstddef>

// Problem constants (match reference)
#define B_   256
#define T_   2048
#define DIM_ 64
#define SGN_ 64              // step-subgroups per block (1024 threads / 16 quads)
#define SPT_ (T_ / SGN_)     // 32 consecutive steps per subgroup
// THETA=0.1, MU=0, SIGMA=1 ; sigma/sqrt(2*theta) = sqrt(5)
#define OU_SCALE 2.2360679774997896f

// Single kernel, single graph node (cross-round ledger: each extra node costs
// ~15-25 us in the timed region — r2's 3-node split gained nothing despite
// -30 us of kernel time; ws-using rounds r1/r7 were slowest). One block per
// row b, 1024 threads = 64 subgroups x 16 dim-quads. vs the r0 monolith:
// phase B is float4 (4x fewer VMEM insts), phase A is per-thread 32-step
// float4 accumulate (independent loads), no idle wave, no scalar replay.
__global__ __launch_bounds__(1024) void fused_kernel(
        const float* __restrict__ ts,
        const float* __restrict__ noise,
        float* __restrict__ out)
{
    __shared__ float4 cofs[T_];        // 32 KB {d_bm, d_ou*sqrt5, f_bm, f_ou}
    __shared__ float4 par[SGN_][16];   // 16 KB subgroup partials

    const int b   = blockIdx.x;
    const int tid = threadIdx.x;
    const int sg  = tid >> 4;          // subgroup 0..63 -> steps [32sg, 32sg+32)
    const int qi  = tid & 15;          // dim quad index
    const int q   = qi << 2;           // dim base (quad within one half)

    // ---- Stage 0: per-step coefficients for row b (2 steps/thread) ----
    const float* tsb = ts + (size_t)b * T_;
    for (int t = tid; t < T_; t += 1024) {
        const float tk = tsb[t];
        const float tp = (t == 0) ? 0.0f : tsb[t - 1];
        const float dt = tk - tp;
        const float db  = sqrtf(dt);
        // exp(2θtk)-exp(2θtp) = exp(2θtp)*expm1(2θ dt)
        const float dou = sqrtf(expf(0.2f * tp) * expm1f(0.2f * dt));
        const float cb = (db  <= 0.0f) ? 0.0f : db;                // *sqrt(sigma)=1
        const float co = (dou <= 0.0f) ? 0.0f : dou * OU_SCALE;
        const float fb = 1.0f / (sqrtf(tk) + 1e-8f);
        const float em = expf(-0.1f * tk);                         // exp(-θ t)
        const float fo = em / (sqrtf(-expm1f(-0.2f * tk) * 5.0f) + 1e-8f);
        cofs[t] = make_float4(cb, co, fb, fo);
    }
    __syncthreads();

    const size_t rowbase = (size_t)b * T_ * DIM_;
    const bool   ou      = q >= (DIM_ / 2);
    const int    tb      = sg * SPT_;
    const float* np = noise + rowbase + (size_t)tb * DIM_ + q;

    // ---- Phase A: weighted float4 partial of this subgroup's 32 steps ----
    {
        float4 a = make_float4(0.f, 0.f, 0.f, 0.f);
#pragma unroll 8
        for (int i = 0; i < SPT_; ++i) {
            const float4 v = *(const float4*)(np + (size_t)i * DIM_);
            const float4 c = cofs[tb + i];
            const float  d = ou ? c.y : c.x;
            a.x = fmaf(d, v.x, a.x);
            a.y = fmaf(d, v.y, a.y);
            a.z = fmaf(d, v.z, a.z);
            a.w = fmaf(d, v.w, a.w);
        }
        par[sg][qi] = a;
    }
    __syncthreads();

    // ---- Exclusive prefix over earlier subgroups (LDS, ~2-way free) ----
    float4 acc = make_float4(0.f, 0.f, 0.f, 0.f);
    for (int k = 0; k < sg; ++k) {
        const float4 p = par[k][qi];
        acc.x += p.x; acc.y += p.y; acc.z += p.z; acc.w += p.w;
    }

    // ---- Phase B: replay (L3-hot re-read), scan, normalize, float4 store ----
    float* op = out + rowbase + (size_t)tb * DIM_ + q;
#pragma unroll 8
    for (int i = 0; i < SPT_; ++i) {
        const float4 v = *(const float4*)(np + (size_t)i * DIM_);
        const float4 c = cofs[tb + i];
        const float  d = ou ? c.y : c.x;
        const float  f = ou ? c.w : c.z;
        acc.x = fmaf(d, v.x, acc.x);
        acc.y = fmaf(d, v.y, acc.y);
        acc.z = fmaf(d, v.z, acc.z);
        acc.w = fmaf(d, v.w, acc.w);
        *(float4*)(op + (size_t)i * DIM_) =
            make_float4(acc.x * f, acc.y * f, acc.z * f, acc.w * f);
    }
}

// ---------------------------------------------------------------------------
extern "C" void kernel_launch(void* const* d_in, const int* in_sizes, int n_in,
                              void* d_out, int out_size, void* d_ws, size_t ws_size,
                              hipStream_t stream) {
    const float* ts    = (const float*)d_in[0];   // [B,T,1] fp32
    const float* noise = (const float*)d_in[1];   // [B,T,DIM] fp32
    float* out = (float*)d_out;                   // [B,T,DIM] fp32
    // d_ws untouched (ws-using rounds r1/r7 were the slowest passers).
    (void)d_ws; (void)ws_size; (void)in_sizes; (void)n_in; (void)out_size;

    fused_kernel<<<B_, 1024, 0, stream>>>(ts, noise, out);
}

// Round 9
// 251.943 us; speedup vs baseline: 1.0477x; 1.0261x over previous
//
#include <hip/hip_runtime.h>
#include <cstddef>

// Problem constants (match reference)
#define B_   256
#define T_   2048
#define DIM_ 64
#define HD_  (DIM_ / 2)      // 32 dims per half
#define SGN_ 128             // step-subgroups per block (1024 threads / 8 quads)
#define SPT_ (T_ / SGN_)     // 16 consecutive steps per subgroup
// THETA=0.1, MU=0, SIGMA=1 ; sigma/sqrt(2*theta) = sqrt(5)
#define OU_SCALE 2.2360679774997896f

// r8 diagnosis: grid=256x1024 (1 block/CU, 16 waves) caps at 2.7 TB/s with
// Occupancy 34% (<50% structural max) -> CUs starve; shape-bound, not
// instruction-bound (r0 scalar and r8 float4 identical at ~99 us).
// Fix: split the independent DIM halves (BM dims 0..31 | OU dims 32..63)
// across blocks. Grid = B*2 = 512 blocks x 1024 threads = exactly 2
// co-resident blocks/CU (32 waves = occupancy ceiling; LDS 32KB/block,
// enforced by launch_bounds(1024,8) -> VGPR<=64). Each block needs only its
// half's coefficients: cofs is float2[T] (16KB), half the transcendentals,
// and no per-element ou?: selects. Per-step 128B access, disjoint cache
// lines between the two half-blocks -> no over-fetch. Single kernel node,
// no workspace (multi-node and ws rounds r1/r2/r5/r7 all regressed).
__global__ __launch_bounds__(1024, 8) void fused_kernel(
        const float* __restrict__ ts,
        const float* __restrict__ noise,
        float* __restrict__ out)
{
    __shared__ float2 cofs[T_];        // 16 KB {delta, norm-factor} for this half
    __shared__ float4 par[SGN_][8];    // 16 KB subgroup partials

    const int bid = blockIdx.x;
    const int b   = bid >> 1;          // row
    const int h   = bid & 1;           // 0 = BM half, 1 = OU half
    const int tid = threadIdx.x;
    const int sg  = tid >> 3;          // subgroup 0..127 -> steps [16sg, 16sg+16)
    const int qi  = tid & 7;           // quad index within the half
    const int q   = (h << 5) + (qi << 2);   // absolute dim base

    // ---- Stage 0: this half's per-step {delta, factor} (2 steps/thread) ----
    const float* tsb = ts + (size_t)b * T_;
    for (int t = tid; t < T_; t += 1024) {
        const float tk = tsb[t];
        const float tp = (t == 0) ? 0.0f : tsb[t - 1];
        float d, f;
        if (h == 0) {                              // Brownian half (cheap)
            const float db = sqrtf(tk - tp);
            d = (db <= 0.0f) ? 0.0f : db;          // * sqrt(sigma)=1
            f = 1.0f / (sqrtf(tk) + 1e-8f);
        } else {                                   // OU half
            // exp(2θtk)-exp(2θtp) = exp(2θtp)*expm1(2θ dt)
            const float dou = sqrtf(expf(0.2f * tp) * expm1f(0.2f * (tk - tp)));
            d = (dou <= 0.0f) ? 0.0f : dou * OU_SCALE;
            const float em = expf(-0.1f * tk);     // exp(-θ t)
            f = em / (sqrtf(-expm1f(-0.2f * tk) * 5.0f) + 1e-8f);
        }
        cofs[t] = make_float2(d, f);
    }
    __syncthreads();

    const size_t rowbase = (size_t)b * T_ * DIM_;
    const int    tb      = sg * SPT_;
    const float* np = noise + rowbase + (size_t)tb * DIM_ + q;

    // ---- Phase A: weighted float4 partial of this subgroup's 16 steps ----
    {
        float4 a = make_float4(0.f, 0.f, 0.f, 0.f);
#pragma unroll
        for (int i = 0; i < SPT_; ++i) {
            const float4 v = *(const float4*)(np + (size_t)i * DIM_);
            const float  d = cofs[tb + i].x;
            a.x = fmaf(d, v.x, a.x);
            a.y = fmaf(d, v.y, a.y);
            a.z = fmaf(d, v.z, a.z);
            a.w = fmaf(d, v.w, a.w);
        }
        par[sg][qi] = a;
    }
    __syncthreads();

    // ---- Exclusive prefix over earlier subgroups (8 quads -> 8 distinct
    //      banks, broadcast across sg groups: conflict-free) ----
    float4 acc = make_float4(0.f, 0.f, 0.f, 0.f);
    for (int k = 0; k < sg; ++k) {
        const float4 p = par[k][qi];
        acc.x += p.x; acc.y += p.y; acc.z += p.z; acc.w += p.w;
    }

    // ---- Phase B: replay (L3-hot re-read), scan, normalize, store ----
    float* op = out + rowbase + (size_t)tb * DIM_ + q;
#pragma unroll
    for (int i = 0; i < SPT_; ++i) {
        const float4 v = *(const float4*)(np + (size_t)i * DIM_);
        const float2 c = cofs[tb + i];
        acc.x = fmaf(c.x, v.x, acc.x);
        acc.y = fmaf(c.x, v.y, acc.y);
        acc.z = fmaf(c.x, v.z, acc.z);
        acc.w = fmaf(c.x, v.w, acc.w);
        *(float4*)(op + (size_t)i * DIM_) =
            make_float4(acc.x * c.y, acc.y * c.y, acc.z * c.y, acc.w * c.y);
    }
}

// ---------------------------------------------------------------------------
extern "C" void kernel_launch(void* const* d_in, const int* in_sizes, int n_in,
                              void* d_out, int out_size, void* d_ws, size_t ws_size,
                              hipStream_t stream) {
    const float* ts    = (const float*)d_in[0];   // [B,T,1] fp32
    const float* noise = (const float*)d_in[1];   // [B,T,DIM] fp32
    float* out = (float*)d_out;                   // [B,T,DIM] fp32
    // d_ws untouched (ws-using rounds were the slowest passers).
    (void)d_ws; (void)ws_size; (void)in_sizes; (void)n_in; (void)out_size;

    fused_kernel<<<B_ * 2, 1024, 0, stream>>>(ts, noise, out);
}

// Round 11
// 251.186 us; speedup vs baseline: 1.0509x; 1.0030x over previous
//
#include <hip/hip_runtime.h>
#include <cstddef>

// Problem constants (match reference)
#define B_   256
#define T_   2048
#define DIM_ 64
#define NT_  16              // tiles per row
#define TS_  128             // steps per tile (1 float4 per thread per tile)
// THETA=0.1, MU=0, SIGMA=1 ; sigma/sqrt(2*theta) = sqrt(5)
#define OU_SCALE 2.2360679774997896f

// r9 post-mortem: occupancy 34->59% moved BW only 2.73->2.89 TB/s while the
// harness's own 512MiB fill streams 6.7 TB/s -> the cap is the barrier-
// separated phase structure (read-all / drain / re-read+write-all bursts),
// not occupancy or instruction mix. This kernel is a single-pass streaming
// scan: per 128-step tile each thread loads ONE float4 (prefetched 2 tiles
// ahead — load addresses are independent of the scan chain, so reads stream
// continuously across tiles while stores fire), scans 8 steps intra-wave via
// 3 shfl rounds, combines 16 wave-totals through LDS with 2 barriers/tile.
// Noise is read ONCE (no phase-B re-read), reads and writes interleave
// continuously like the copy ubench. Exterior kept from r9 (best so far):
// single node, (row,half) blocks, 512 x 1024, 2 blocks/CU, no workspace.
__global__ __launch_bounds__(1024, 8) void stream_kernel(
        const float* __restrict__ ts,
        const float* __restrict__ noise,
        float* __restrict__ out)
{
    __shared__ float2 cofs[T_];        // 16 KB {delta, norm-factor} this half
    __shared__ float4 wtot[16][9];     // wave totals, padded: banks qi*4+k*4

    const int bid  = blockIdx.x;
    const int b    = bid >> 1;         // row
    const int h    = bid & 1;          // 0 = BM half, 1 = OU half
    const int tid  = threadIdx.x;
    const int st   = tid >> 3;         // step-in-tile 0..127
    const int qi   = tid & 7;          // quad within the half
    const int q    = (h << 5) + (qi << 2);
    const int w    = tid >> 6;         // wave 0..15 (owns st = 8w..8w+7)
    const int sl   = st & 7;           // st-local within wave
    const int lane = tid & 63;

    // ---- Stage 0: this half's per-step {delta, factor} (2 steps/thread) ----
    const float* tsb = ts + (size_t)b * T_;
    for (int t = tid; t < T_; t += 1024) {
        const float tk = tsb[t];
        const float tp = (t == 0) ? 0.0f : tsb[t - 1];
        float d, f;
        if (h == 0) {                              // Brownian half
            const float db = sqrtf(tk - tp);
            d = (db <= 0.0f) ? 0.0f : db;          // * sqrt(sigma)=1
            f = 1.0f / (sqrtf(tk) + 1e-8f);
        } else {                                   // OU half
            // exp(2θtk)-exp(2θtp) = exp(2θtp)*expm1(2θ dt)
            const float dou = sqrtf(expf(0.2f * tp) * expm1f(0.2f * (tk - tp)));
            d = (dou <= 0.0f) ? 0.0f : dou * OU_SCALE;
            const float em = expf(-0.1f * tk);     // exp(-θ t)
            f = em / (sqrtf(-expm1f(-0.2f * tk) * 5.0f) + 1e-8f);
        }
        cofs[t] = make_float2(d, f);
    }
    __syncthreads();

    const size_t rowbase = (size_t)b * T_ * DIM_;
    const float* np = noise + rowbase + q;         // index by t*DIM_
    float*       op = out   + rowbase + q;

    // register prefetch, depth 2 (addresses independent of scan chain)
    float4 v0 = *(const float4*)(np + (size_t)(0 * TS_ + st) * DIM_);
    float4 v1 = *(const float4*)(np + (size_t)(1 * TS_ + st) * DIM_);

    float4 base = make_float4(0.f, 0.f, 0.f, 0.f);

    for (int j = 0; j < NT_; ++j) {
        float4 v2 = make_float4(0.f, 0.f, 0.f, 0.f);
        if (j + 2 < NT_)
            v2 = *(const float4*)(np + (size_t)((j + 2) * TS_ + st) * DIM_);

        const int    t = j * TS_ + st;
        const float2 c = cofs[t];

        // weighted value for this step
        float4 s = make_float4(c.x * v0.x, c.x * v0.y, c.x * v0.z, c.x * v0.w);

        // inclusive scan along st within the wave (8 steps, lane stride 8)
#pragma unroll
        for (int d = 1; d <= 4; d <<= 1) {
            const int src = lane - (d << 3);
            const float tx = __shfl(s.x, src, 64);
            const float ty = __shfl(s.y, src, 64);
            const float tz = __shfl(s.z, src, 64);
            const float tw = __shfl(s.w, src, 64);
            if (sl >= d) { s.x += tx; s.y += ty; s.z += tz; s.w += tw; }
        }

        // wave totals (inclusive value at sl==7) -> LDS
        if (sl == 7) wtot[w][qi] = s;
        __syncthreads();

        // exclusive wave base + tile total (broadcast reads, conflict-free)
        float4 wb = make_float4(0.f, 0.f, 0.f, 0.f);
        float4 tt = make_float4(0.f, 0.f, 0.f, 0.f);
#pragma unroll
        for (int k = 0; k < 16; ++k) {
            const float4 p = wtot[k][qi];
            if (k < w) { wb.x += p.x; wb.y += p.y; wb.z += p.z; wb.w += p.w; }
            tt.x += p.x; tt.y += p.y; tt.z += p.z; tt.w += p.w;
        }

        // normalize + store
        const float f = c.y;
        const float4 o = make_float4((base.x + wb.x + s.x) * f,
                                     (base.y + wb.y + s.y) * f,
                                     (base.z + wb.z + s.z) * f,
                                     (base.w + wb.w + s.w) * f);
        *(float4*)(op + (size_t)t * DIM_) = o;

        base.x += tt.x; base.y += tt.y; base.z += tt.z; base.w += tt.w;
        __syncthreads();               // protect wtot before next tile's write
        v0 = v1; v1 = v2;
    }
}

// ---------------------------------------------------------------------------
extern "C" void kernel_launch(void* const* d_in, const int* in_sizes, int n_in,
                              void* d_out, int out_size, void* d_ws, size_t ws_size,
                              hipStream_t stream) {
    const float* ts    = (const float*)d_in[0];   // [B,T,1] fp32
    const float* noise = (const float*)d_in[1];   // [B,T,DIM] fp32
    float* out = (float*)d_out;                   // [B,T,DIM] fp32
    // d_ws untouched (ws-using rounds were the slowest passers).
    (void)d_ws; (void)ws_size; (void)in_sizes; (void)n_in; (void)out_size;

    stream_kernel<<<B_ * 2, 1024, 0, stream>>>(ts, noise, out);
}